// Round 7
// baseline (404.795 us; speedup 1.0000x reference)
//
#include <hip/hip_runtime.h>
#include <hip/hip_bf16.h>

// GraphSAGE 3-layer: 40 -> 64 -> 128 -> 3, mean aggregation over fixed edges.
// R7: k_fill_part's remaining 73MB writes = partial-line writebacks caused by
// the 12.8MB src/dst stream evicting dirty csr lines from the partition's L2.
// Fix: nontemporal loads for the edge streams (k_fill_part, k_deg) so the
// write path keeps L2 to itself; blocks_per_part 96->128.

static constexpr int NN = 100000;
static constexpr int EE = 1600000;
static constexpr int NB = (NN + 255) / 256;   // 391 scan blocks
static constexpr int NPART = 8;
static constexpr int PSIZE = (NN + NPART - 1) / NPART;   // 12500

typedef __attribute__((ext_vector_type(8))) short short8;
typedef __attribute__((ext_vector_type(4))) float f32x4;

__device__ __forceinline__ float bf2f(unsigned short u) {
    union { unsigned int i; float f; } c; c.i = ((unsigned int)u) << 16; return c.f;
}
__device__ __forceinline__ unsigned short f2bf(float f) {
    union { float f; unsigned int i; } c; c.f = f;
    unsigned int x = c.i;
    return (unsigned short)((x + 0x7fffu + ((x >> 16) & 1u)) >> 16);   // RNE
}

// ---------------- degree histogram (nt reads: don't pollute L2) ----------------
__global__ __launch_bounds__(256) void k_deg(const int* __restrict__ dst, int* __restrict__ deg) {
    int e = blockIdx.x * 256 + threadIdx.x;
    if (e < EE) atomicAdd(&deg[__builtin_nontemporal_load(dst + e)], 1);
}

// ---------------- hierarchical scan: block sums ----------------
__global__ __launch_bounds__(256) void k_bsum(const int* __restrict__ deg, int* __restrict__ bsum) {
    int i = blockIdx.x * 256 + threadIdx.x;
    int v = (i < NN) ? deg[i] : 0;
    int lane = threadIdx.x & 63, wid = threadIdx.x >> 6;
#pragma unroll
    for (int d = 32; d; d >>= 1) v += __shfl_down(v, d, 64);
    __shared__ int wsum[4];
    if (lane == 0) wsum[wid] = v;
    __syncthreads();
    if (threadIdx.x == 0) bsum[blockIdx.x] = wsum[0] + wsum[1] + wsum[2] + wsum[3];
}

// ---------------- scan of 391 block sums (one block) ----------------
__global__ __launch_bounds__(512) void k_bscan(const int* __restrict__ bsum, int* __restrict__ boff,
                                               int* __restrict__ row_start) {
    __shared__ int s[512];
    int tid = threadIdx.x;
    int v = (tid < NB) ? bsum[tid] : 0;
    s[tid] = v;
    __syncthreads();
    for (int d = 1; d < 512; d <<= 1) {
        int t = (tid >= d) ? s[tid - d] : 0;
        __syncthreads();
        s[tid] += t;
        __syncthreads();
    }
    if (tid < NB) boff[tid] = s[tid] - v;   // exclusive
    if (tid == 0) row_start[NN] = EE;
}

// ---------------- final scan: row_start + deg_inv ----------------
__global__ __launch_bounds__(256) void k_scan2(const int* __restrict__ deg, const int* __restrict__ boff,
                                               int* __restrict__ row_start, float* __restrict__ deg_inv) {
    int tid = threadIdx.x, lane = tid & 63, wid = tid >> 6;
    int i = blockIdx.x * 256 + tid;
    int v = (i < NN) ? deg[i] : 0;
    int inc = v;
#pragma unroll
    for (int d = 1; d < 64; d <<= 1) {
        int t = __shfl_up(inc, d, 64);
        if (lane >= d) inc += t;
    }
    __shared__ int wsum[4];
    if (lane == 63) wsum[wid] = inc;
    __syncthreads();
    if (tid == 0) {
        int s = 0;
#pragma unroll
        for (int j = 0; j < 4; ++j) { int t = wsum[j]; wsum[j] = s; s += t; }
    }
    __syncthreads();
    if (i < NN) {
        row_start[i] = boff[blockIdx.x] + wsum[wid] + (inc - v);
        deg_inv[i] = (v > 0) ? 1.0f / (float)v : 0.0f;
    }
}

// ---------------- CSR scatter, XCD-partitioned by dst range ----------------
// partition = blockIdx%8 (round-robin block->XCD): all writes to a csr line
// come from one XCD's L2. Edge streams read nontemporally so they don't evict
// the partially-written csr lines.
__global__ __launch_bounds__(256) void k_fill_part(const int* __restrict__ src, const int* __restrict__ dst,
                                                   const int* __restrict__ row_start, int* __restrict__ cursor,
                                                   int* __restrict__ csr_src, int blocks_per_part) {
    const int part = blockIdx.x & (NPART - 1);
    const int bp = blockIdx.x >> 3;
    const int lo = part * PSIZE;
    const int hi = (lo + PSIZE < NN) ? lo + PSIZE : NN;
    const int chunk = (EE + blocks_per_part - 1) / blocks_per_part;
    const int e0 = bp * chunk;
    const int e1 = (e0 + chunk < EE) ? e0 + chunk : EE;
    for (int e = e0 + threadIdx.x; e < e1; e += 256) {
        int d = __builtin_nontemporal_load(dst + e);
        if (d >= lo && d < hi) {
            int s = __builtin_nontemporal_load(src + e);
            int pos = atomicAdd(&cursor[d], 1);
            csr_src[row_start[d] + pos] = s;
        }
    }
}

// ---------------- fp32 -> bf16 row convert (x: N x 40) ----------------
__global__ __launch_bounds__(256) void k_cvt(const float* __restrict__ x, unsigned short* __restrict__ xb) {
    int i = blockIdx.x * 256 + threadIdx.x;            // groups of 8 elems
    if (i >= NN * 40 / 8) return;
    const float4* p = (const float4*)(x + (size_t)i * 8);
    float4 a = p[0], b = p[1];
    short8 v;
    v[0] = (short)f2bf(a.x); v[1] = (short)f2bf(a.y); v[2] = (short)f2bf(a.z); v[3] = (short)f2bf(a.w);
    v[4] = (short)f2bf(b.x); v[5] = (short)f2bf(b.y); v[6] = (short)f2bf(b.z); v[7] = (short)f2bf(b.w);
    *(short8*)(xb + (size_t)i * 8) = v;
}

// ---------------- bf16 mean-aggregate into concat A = [mean(FinP) | root(FinP)] ----------------
template<int Fin, int FinP>
__global__ __launch_bounds__(256) void k_meanb(const unsigned short* __restrict__ xin,
                                               const int* __restrict__ row_start,
                                               const int* __restrict__ csr_src,
                                               const float* __restrict__ deg_inv,
                                               unsigned short* __restrict__ Acat) {
    constexpr int CH = Fin / 8;     // data chunks (5 or 8)
    constexpr int PCH = FinP / 8;   // padded chunks (6 or 8)
    constexpr int K2 = 2 * FinP;
    int gid = blockIdx.x * 256 + threadIdx.x;
    int node = gid >> 3;
    int c = gid & 7;
    if (node >= NN) return;
    float acc[8] = {0, 0, 0, 0, 0, 0, 0, 0};
    if (c < CH) {
        const unsigned short* xq = xin + c * 8;
        int rs = row_start[node], re = row_start[node + 1];
        int k = rs;
        for (; k + 4 <= re; k += 4) {
            int s0 = csr_src[k], s1 = csr_src[k + 1], s2 = csr_src[k + 2], s3 = csr_src[k + 3];
            short8 v0 = *(const short8*)(xq + (size_t)s0 * Fin);
            short8 v1 = *(const short8*)(xq + (size_t)s1 * Fin);
            short8 v2 = *(const short8*)(xq + (size_t)s2 * Fin);
            short8 v3 = *(const short8*)(xq + (size_t)s3 * Fin);
#pragma unroll
            for (int j = 0; j < 8; ++j)
                acc[j] += (bf2f((unsigned short)v0[j]) + bf2f((unsigned short)v1[j]))
                        + (bf2f((unsigned short)v2[j]) + bf2f((unsigned short)v3[j]));
        }
        for (; k < re; ++k) {
            short8 v0 = *(const short8*)(xq + (size_t)csr_src[k] * Fin);
#pragma unroll
            for (int j = 0; j < 8; ++j) acc[j] += bf2f((unsigned short)v0[j]);
        }
        float di = deg_inv[node];
#pragma unroll
        for (int j = 0; j < 8; ++j) acc[j] *= di;
    }
    if (c < PCH) {
        short8 m;
#pragma unroll
        for (int j = 0; j < 8; ++j) m[j] = (c < CH) ? (short)f2bf(acc[j]) : (short)0;
        *(short8*)(Acat + (size_t)node * K2 + c * 8) = m;
        short8 rv;
        if (c < CH) {
            rv = *(const short8*)(xin + (size_t)node * Fin + c * 8);
        } else {
#pragma unroll
            for (int j = 0; j < 8; ++j) rv[j] = 0;
        }
        *(short8*)(Acat + (size_t)node * K2 + FinP + c * 8) = rv;
    }
}

// ---------------- MFMA GEMM: out = relu?(A @ [Wl;Wr]^T + b), A = N x 2FinP bf16 ----------------
template<int Fin, int FinP, int Fout, bool RELU>
__global__ __launch_bounds__(256) void k_gemm(const unsigned short* __restrict__ A,
                                              const float* __restrict__ Wl,
                                              const float* __restrict__ bias,
                                              const float* __restrict__ Wr,
                                              unsigned short* __restrict__ out) {
    constexpr int K = 2 * FinP;
    constexpr int KS = K / 32;
    constexpr int TILES = Fout / 16;
    __shared__ short sB[TILES * KS * 64 * 8];
    const int lane = threadIdx.x & 63;
    for (int idx = threadIdx.x; idx < TILES * KS * 64; idx += 256) {
        int l = idx & 63;
        int ks = (idx >> 6) % KS;
        int t = idx / (64 * KS);
        int o = t * 16 + (l & 15);
        int kbase = ks * 32 + (l >> 4) * 8;
        short8 v;
#pragma unroll
        for (int j = 0; j < 8; ++j) {
            int k = kbase + j;
            float w;
            if (k < FinP) w = (k < Fin) ? Wl[(size_t)o * Fin + k] : 0.f;
            else { int k2 = k - FinP; w = (k2 < Fin) ? Wr[(size_t)o * Fin + k2] : 0.f; }
            v[j] = (short)f2bf(w);
        }
        *(short8*)&sB[idx * 8] = v;
    }
    __syncthreads();
    float bias_t[TILES];
#pragma unroll
    for (int t = 0; t < TILES; ++t) bias_t[t] = bias[t * 16 + (lane & 15)];

    const int wave = blockIdx.x * 4 + (threadIdx.x >> 6);
    const int nchunks = NN / 32;                        // 3125
    for (int ci = wave; ci < nchunks; ci += gridDim.x * 4) {
        int nbase = ci * 32;
        const unsigned short* a0 = A + (size_t)(nbase + (lane & 15)) * K + (lane >> 4) * 8;
        short8 af[2][KS];
#pragma unroll
        for (int ks = 0; ks < KS; ++ks) {
            af[0][ks] = *(const short8*)(a0 + ks * 32);
            af[1][ks] = *(const short8*)(a0 + 16 * K + ks * 32);
        }
        f32x4 acc[2][TILES];
#pragma unroll
        for (int m = 0; m < 2; ++m)
#pragma unroll
            for (int t = 0; t < TILES; ++t) acc[m][t] = (f32x4){0.f, 0.f, 0.f, 0.f};
#pragma unroll
        for (int t = 0; t < TILES; ++t)
#pragma unroll
            for (int ks = 0; ks < KS; ++ks) {
                short8 bf = *(const short8*)&sB[((t * KS + ks) * 64 + lane) * 8];
                acc[0][t] = __builtin_amdgcn_mfma_f32_16x16x32_bf16(af[0][ks], bf, acc[0][t], 0, 0, 0);
                acc[1][t] = __builtin_amdgcn_mfma_f32_16x16x32_bf16(af[1][ks], bf, acc[1][t], 0, 0, 0);
            }
#pragma unroll
        for (int m = 0; m < 2; ++m) {
            int nrow = nbase + m * 16 + (lane >> 4) * 4;
#pragma unroll
            for (int t = 0; t < TILES; ++t) {
                int col = t * 16 + (lane & 15);
#pragma unroll
                for (int r = 0; r < 4; ++r) {
                    float v = acc[m][t][r] + bias_t[t];
                    if (RELU) v = fmaxf(v, 0.f);
                    out[(size_t)(nrow + r) * Fout + col] = f2bf(v);
                }
            }
        }
    }
}

// ---------------- layer 3 transforms: z = h2@W4l.T, r = h2@W4r.T (h2 bf16) ----------------
__global__ __launch_bounds__(256) void k_zr(const unsigned short* __restrict__ h2,
                                            const float* __restrict__ W4l, const float* __restrict__ W4r,
                                            float* __restrict__ z, float* __restrict__ r) {
    int node = (blockIdx.x * 256 + threadIdx.x) >> 6;
    int lane = threadIdx.x & 63;
    if (node >= NN) return;
    float h0 = bf2f(h2[(size_t)node * 128 + lane]);
    float h1v = bf2f(h2[(size_t)node * 128 + 64 + lane]);
    float zc0 = h0 * W4l[0 * 128 + lane] + h1v * W4l[0 * 128 + 64 + lane];
    float zc1 = h0 * W4l[1 * 128 + lane] + h1v * W4l[1 * 128 + 64 + lane];
    float zc2 = h0 * W4l[2 * 128 + lane] + h1v * W4l[2 * 128 + 64 + lane];
    float rc0 = h0 * W4r[0 * 128 + lane] + h1v * W4r[0 * 128 + 64 + lane];
    float rc1 = h0 * W4r[1 * 128 + lane] + h1v * W4r[1 * 128 + 64 + lane];
    float rc2 = h0 * W4r[2 * 128 + lane] + h1v * W4r[2 * 128 + 64 + lane];
#pragma unroll
    for (int d = 32; d; d >>= 1) {
        zc0 += __shfl_down(zc0, d, 64); zc1 += __shfl_down(zc1, d, 64); zc2 += __shfl_down(zc2, d, 64);
        rc0 += __shfl_down(rc0, d, 64); rc1 += __shfl_down(rc1, d, 64); rc2 += __shfl_down(rc2, d, 64);
    }
    if (lane == 0) {
        *(float4*)&z[(size_t)node * 4] = make_float4(zc0, zc1, zc2, 0.f);
        *(float4*)&r[(size_t)node * 4] = make_float4(rc0, rc1, rc2, 0.f);
    }
}

// ---------------- final: out = mean(z)[n] + r[n] + b4 ----------------
__global__ __launch_bounds__(256) void k_final(const float* __restrict__ z, const float* __restrict__ r,
                                               const float* __restrict__ b4,
                                               const int* __restrict__ row_start, const int* __restrict__ csr_src,
                                               const float* __restrict__ deg_inv, float* __restrict__ out) {
    int n = blockIdx.x * 256 + threadIdx.x;
    if (n >= NN) return;
    int rs = row_start[n], re = row_start[n + 1];
    float a0 = 0, a1 = 0, a2 = 0, b0 = 0, b1 = 0, b2 = 0;
    int k = rs;
    for (; k + 4 <= re; k += 4) {
        int s0 = csr_src[k], s1 = csr_src[k + 1], s2 = csr_src[k + 2], s3 = csr_src[k + 3];
        float4 z0 = *(const float4*)&z[4 * (size_t)s0];
        float4 z1 = *(const float4*)&z[4 * (size_t)s1];
        float4 z2 = *(const float4*)&z[4 * (size_t)s2];
        float4 z3 = *(const float4*)&z[4 * (size_t)s3];
        a0 += z0.x; a1 += z0.y; a2 += z0.z;
        b0 += z1.x; b1 += z1.y; b2 += z1.z;
        a0 += z2.x; a1 += z2.y; a2 += z2.z;
        b0 += z3.x; b1 += z3.y; b2 += z3.z;
    }
    for (; k < re; ++k) {
        float4 z0 = *(const float4*)&z[4 * (size_t)csr_src[k]];
        a0 += z0.x; a1 += z0.y; a2 += z0.z;
    }
    float di = deg_inv[n];
    float4 rn = *(const float4*)&r[4 * (size_t)n];
    out[(size_t)n * 3 + 0] = (a0 + b0) * di + rn.x + b4[0];
    out[(size_t)n * 3 + 1] = (a1 + b1) * di + rn.y + b4[1];
    out[(size_t)n * 3 + 2] = (a2 + b2) * di + rn.z + b4[2];
}

extern "C" void kernel_launch(void* const* d_in, const int* in_sizes, int n_in,
                              void* d_out, int out_size, void* d_ws, size_t ws_size,
                              hipStream_t stream) {
    const float* x   = (const float*)d_in[0];
    const int*   ei  = (const int*)d_in[1];
    const float* W1l = (const float*)d_in[2];
    const float* b1  = (const float*)d_in[3];
    const float* W1r = (const float*)d_in[4];
    const float* W2l = (const float*)d_in[5];
    const float* b2  = (const float*)d_in[6];
    const float* W2r = (const float*)d_in[7];
    const float* W4l = (const float*)d_in[8];
    const float* b4  = (const float*)d_in[9];
    const float* W4r = (const float*)d_in[10];
    float* out = (float*)d_out;

    char* ws = (char*)d_ws;
    size_t off = 0;
    auto alloc = [&](size_t bytes) -> void* {
        void* p = ws + off;
        off = (off + bytes + 255) & ~(size_t)255;
        return p;
    };
    int*   deg       = (int*)alloc((size_t)NN * 4);
    int*   row_start = (int*)alloc(((size_t)NN + 1) * 4);
    int*   cursor    = (int*)alloc((size_t)NN * 4);
    int*   csr_src   = (int*)alloc((size_t)EE * 4);
    float* deg_inv   = (float*)alloc((size_t)NN * 4);
    int*   bsum      = (int*)alloc((size_t)NB * 4);
    int*   boff      = (int*)alloc((size_t)NB * 4);
    unsigned short* xb    = (unsigned short*)alloc((size_t)NN * 40 * 2);
    unsigned short* A1cat = (unsigned short*)alloc((size_t)NN * 96 * 2);
    unsigned short* h1    = (unsigned short*)alloc((size_t)NN * 64 * 2);
    unsigned short* A2cat = (unsigned short*)alloc((size_t)NN * 128 * 2);
    unsigned short* h2    = (unsigned short*)alloc((size_t)NN * 128 * 2);
    float* zbuf = (float*)alloc((size_t)NN * 4 * 4);
    float* rbuf = (float*)alloc((size_t)NN * 4 * 4);

    const int* e_src = ei;
    const int* e_dst = ei + EE;

    hipMemsetAsync(deg, 0, (size_t)NN * 4, stream);
    hipMemsetAsync(cursor, 0, (size_t)NN * 4, stream);

    k_deg<<<(EE + 255) / 256, 256, 0, stream>>>(e_dst, deg);
    k_cvt<<<((NN * 40 / 8) + 255) / 256, 256, 0, stream>>>(x, xb);
    k_bsum<<<NB, 256, 0, stream>>>(deg, bsum);
    k_bscan<<<1, 512, 0, stream>>>(bsum, boff, row_start);
    k_scan2<<<NB, 256, 0, stream>>>(deg, boff, row_start, deg_inv);

    const int blocks_per_part = 128;   // 1024 blocks total
    k_fill_part<<<NPART * blocks_per_part, 256, 0, stream>>>(e_src, e_dst, row_start, cursor, csr_src, blocks_per_part);

    const int mean_blocks = ((size_t)NN * 8 + 255) / 256;   // 3125
    const int gemm_blocks = 782;

    // layer 1: 40 -> 64  (K = 2*48 = 96)
    k_meanb<40, 48><<<mean_blocks, 256, 0, stream>>>(xb, row_start, csr_src, deg_inv, A1cat);
    k_gemm<40, 48, 64, true><<<gemm_blocks, 256, 0, stream>>>(A1cat, W1l, b1, W1r, h1);

    // layer 2: 64 -> 128  (K = 128)
    k_meanb<64, 64><<<mean_blocks, 256, 0, stream>>>(h1, row_start, csr_src, deg_inv, A2cat);
    k_gemm<64, 64, 128, true><<<gemm_blocks, 256, 0, stream>>>(A2cat, W2l, b2, W2r, h2);

    // layer 3: 128 -> 3, transform-before-gather
    k_zr<<<((size_t)NN * 64 + 255) / 256, 256, 0, stream>>>(h2, W4l, W4r, zbuf, rbuf);
    k_final<<<(NN + 255) / 256, 256, 0, stream>>>(zbuf, rbuf, b4, row_start, csr_src, deg_inv, out);
}